// Round 14
// baseline (568.547 us; speedup 1.0000x reference)
//
#include <hip/hip_runtime.h>
#include <stdint.h>

#define VOCABN 8000
#define EE     300
#define HH     75
#define G4     300   // 4*H
#define TT     6
#define BB     256
#define SS     512
#define STARTT 4
#define STOPT  5
#define NEGV   (-10000.0f)
#define NCH    16    // CRF chunks
#define CHL    32    // steps per chunk

typedef __fp16 fp16x2 __attribute__((ext_vector_type(2)));
typedef __fp16 f16x4 __attribute__((ext_vector_type(4)));
typedef __fp16 f16x8 __attribute__((ext_vector_type(8)));
typedef float f32x4 __attribute__((ext_vector_type(4)));
typedef unsigned int u32;
typedef unsigned short u16;

__device__ __forceinline__ float sigf(float x){
  return __builtin_amdgcn_rcpf(1.0f + __expf(-x));
}
__device__ __forceinline__ float tanhf_(float x){
  return __builtin_fmaf(__builtin_amdgcn_rcpf(1.0f + __expf(-2.0f * x)), 2.0f, -1.0f);
}
__device__ __forceinline__ float pk2(float a, float b){
  fp16x2 r = __builtin_amdgcn_cvt_pkrtz(a, b);
  return __builtin_bit_cast(float, r);
}
__device__ __forceinline__ float dot2pk(float a, float b, float c){
  asm("v_dot2_f32_f16 %0, %1, %2, %0" : "+v"(c) : "v"(a), "v"(b));
  return c;
}
// raw barrier: orders LDS, leaves global prefetches in flight
__device__ __forceinline__ void sync_lds(){
  __builtin_amdgcn_sched_barrier(0);
  asm volatile("s_waitcnt lgkmcnt(0)" ::: "memory");
  __builtin_amdgcn_s_barrier();
  __builtin_amdgcn_sched_barrier(0);
}

// ---------------- K1: MFMA f16 GEMM -> vxg[dir][v][g'] (permuted, f16) ------
// C[64v x 300g] per block = emb[64][300] . w_perm[300][300]^T, K chunks of 32.
// Fragment recipe identical to the HW-validated k_lstm one:
//   A: lane(q,bb) m=16w+bb, k=32c+8q+j ; B staged in LDS fragment-order
//   (lane reads at byte lane*16, conflict-free) ; D: row=4q+r, col=bb.
__global__ __launch_bounds__(256) void k_gemm(
    const float* __restrict__ emb, const float* __restrict__ w_ih_f,
    const float* __restrict__ w_ih_b,
    const float* __restrict__ b_ih_f, const float* __restrict__ b_hh_f,
    const float* __restrict__ b_ih_b, const float* __restrict__ b_hh_b,
    __fp16* __restrict__ vxg){
  __shared__ alignas(16) __fp16 bfrag[19 * 64 * 8];   // [gtile][lane][j]
  __shared__ float bias_sh[304];
  const int bx = blockIdx.x;
  const int dir = bx / 125;
  const int vblk = bx % 125;
  const int v0 = vblk * 64;
  const int tid = threadIdx.x;
  const int w = tid >> 6, lane = tid & 63;
  const int bb = lane & 15, q = lane >> 4;
  const float* wdir = dir ? w_ih_b : w_ih_f;

  for (int g = tid; g < 304; g += 256){
    float bi = 0.f;
    if (g < G4){
      int gs = (g & 3) * 75 + (g >> 2);
      bi = dir ? (b_ih_b[gs] + b_hh_b[gs]) : (b_ih_f[gs] + b_hh_f[gs]);
    }
    bias_sh[g] = bi;
  }

  f32x4 acc[19];
  #pragma unroll
  for (int t = 0; t < 19; ++t) acc[t] = (f32x4){0.f, 0.f, 0.f, 0.f};

  const float* arow = emb + (size_t)(v0 + 16 * w + bb) * EE;

  for (int c = 0; c < 10; ++c){
    // ---- A fragment (global f32 -> f16x8) ----
    f16x8 afrag;
    const int kb = 32 * c + 8 * q;
    if (c < 9){
      float4 x0 = *(const float4*)(arow + kb);
      float4 x1 = *(const float4*)(arow + kb + 4);
      afrag[0] = (__fp16)x0.x; afrag[1] = (__fp16)x0.y;
      afrag[2] = (__fp16)x0.z; afrag[3] = (__fp16)x0.w;
      afrag[4] = (__fp16)x1.x; afrag[5] = (__fp16)x1.y;
      afrag[6] = (__fp16)x1.z; afrag[7] = (__fp16)x1.w;
    } else {
      #pragma unroll
      for (int j = 0; j < 8; ++j)
        afrag[j] = (kb + j < EE) ? (__fp16)arow[kb + j] : (__fp16)0.f;
    }

    // ---- stage B chunk into fragment-order LDS ----
    for (int g = tid; g < 304; g += 256){
      int t = g >> 4, col = g & 15;
      bool valid = g < G4;
      const float* wrow = wdir + (size_t)(valid ? ((g & 3) * 75 + (g >> 2)) : 0) * EE;
      #pragma unroll
      for (int qq = 0; qq < 4; ++qq){
        f16x8 tmp;
        #pragma unroll
        for (int j = 0; j < 8; ++j){
          int kk = 32 * c + 8 * qq + j;
          tmp[j] = (valid && kk < EE) ? (__fp16)wrow[kk] : (__fp16)0.f;
        }
        *(f16x8*)&bfrag[(t * 64 + qq * 16 + col) * 8] = tmp;
      }
    }
    __syncthreads();

    // ---- 19 MFMAs against the staged chunk ----
    #pragma unroll
    for (int t = 0; t < 19; ++t){
      f16x8 bf = *(const f16x8*)&bfrag[(t * 64 + lane) * 8];
      asm("v_mfma_f32_16x16x32_f16 %0, %1, %2, %0"
          : "+v"(acc[t]) : "v"(afrag), "v"(bf));
    }
    __syncthreads();
  }

  const size_t obase = (size_t)dir * VOCABN * G4;
  #pragma unroll
  for (int t = 0; t < 19; ++t){
    int g = 16 * t + bb;
    if (g < G4){
      float bi = bias_sh[g];
      #pragma unroll
      for (int r = 0; r < 4; ++r){
        int v = v0 + 16 * w + 4 * q + r;
        vxg[obase + (size_t)v * G4 + g] = (__fp16)(acc[t][r] + bi);
      }
    }
  }
}

// ---------------- K2: MFMA BiLSTM, 16 batch per block (r13, unchanged) ------
__global__ __launch_bounds__(640) void k_lstm(
    const int* __restrict__ sentence, const __fp16* __restrict__ vxg,
    const float* __restrict__ w_hh_f, const float* __restrict__ w_hh_b,
    const float* __restrict__ h0, const float* __restrict__ c0,
    const float* __restrict__ w_out, const float* __restrict__ b_out,
    float* __restrict__ featsF, float* __restrict__ featsB){
  __shared__ u16 tok_sh[SS * 16];
  __shared__ alignas(16) __fp16 hfrag[2][12 * 16 * 8];   // [buf][k>>3][bb][k&7]
  const int bx = blockIdx.x;
  const int dir = bx >> 4, group = bx & 15;
  const int t = threadIdx.x;
  const int w = t >> 6, lane = t & 63;
  const int bb = lane & 15, q = lane >> 4;
  const int T0 = 2 * w, T1 = 2 * w + 1;
  const int rbA = 16 * T0 + 4 * q, rbB = 16 * T1 + 4 * q;
  const int hA = rbA >> 2, hB = rbB >> 2;      // hA = 8w+q, hB = 8w+4+q
  const int bglob = group * 16 + bb;
  const int wiA = w * 128 + bb * 8 + q;        // fragment-order write indices
  const int wiB = w * 128 + bb * 8 + 4 + q;

  for (int i = t; i < 2 * 12 * 16 * 4; i += 640) ((u32*)hfrag)[i] = 0;
  for (int i = t; i < 16 * SS; i += 640){
    int bq = i >> 9, s = i & 511;
    tok_sh[s * 16 + ((bq + s) & 15)] =
        (u16)sentence[(size_t)(group * 16 + bq) * SS + s];
  }
  __syncthreads();

  const float* whh = dir ? w_hh_b : w_hh_f;
  f16x8 a00, a01, a02, a10, a11, a12;
  #define BUILD_A(dst, T, c) { \
    int m = 16 * (T) + bb; int kb = 32 * (c) + 8 * q; \
    _Pragma("unroll") \
    for (int j = 0; j < 8; ++j){ \
      int kk = kb + j; float wv = 0.f; \
      if (kk < HH){ \
        if (m < 300) wv = whh[((m & 3) * 75 + (m >> 2)) * HH + kk]; \
        else if (m < 306) wv = w_out[(m - 300) * (2 * HH) + dir * HH + kk]; \
      } \
      dst[j] = (__fp16)wv; } }
  BUILD_A(a00, T0, 0) BUILD_A(a01, T0, 1) BUILD_A(a02, T0, 2)
  BUILD_A(a10, T1, 0) BUILD_A(a11, T1, 1) BUILD_A(a12, T1, 2)

  float cA = 0.f, cB = 0.f;
  if (hA < HH){
    cA = c0[((size_t)dir * BB + bglob) * HH + hA];
    hfrag[0][wiA] = (__fp16)h0[((size_t)dir * BB + bglob) * HH + hA];
  }
  if (hB < HH){
    cB = c0[((size_t)dir * BB + bglob) * HH + hB];
    hfrag[0][wiB] = (__fp16)h0[((size_t)dir * BB + bglob) * HH + hB];
  }
  const float bo0 = dir ? 0.f : b_out[0], bo1 = dir ? 0.f : b_out[1];
  const float bo2 = dir ? 0.f : b_out[2], bo3 = dir ? 0.f : b_out[3];
  const float bo4 = dir ? 0.f : b_out[4], bo5 = dir ? 0.f : b_out[5];
  __syncthreads();

  const __fp16* vx = vxg + (size_t)dir * VOCABN * G4;
  float* feats = dir ? featsB : featsF;
  const f16x4 zh4 = {(__fp16)0.f, (__fp16)0.f, (__fp16)0.f, (__fp16)0.f};

#define LOADPAIR(d0, d1, kstep) { \
    if ((kstep) < SS){ \
      int sr_ = dir ? (SS - 1 - (kstep)) : (kstep); \
      int tk_ = tok_sh[sr_ * 16 + ((bb + sr_) & 15)]; \
      const __fp16* base_ = vx + (size_t)tk_ * G4; \
      d0 = (hA < HH) ? *(const f16x4*)(base_ + rbA) : zh4; \
      d1 = (hB < HH) ? *(const f16x4*)(base_ + rbB) : zh4; \
    } else { d0 = zh4; d1 = zh4; } }

  f16x4 cur0, cur1, nx0, nx1, p0, p1;
  LOADPAIR(cur0, cur1, 0)
  LOADPAIR(nx0, nx1, 1)

  for (int k = 0; k <= SS; ++k){
    const __fp16* hq = hfrag[k & 1];
    f16x8 b0 = *(const f16x8*)&hq[(0 * 64 + lane) * 8];   // byte addr = lane*16
    f16x8 b1 = *(const f16x8*)&hq[(1 * 64 + lane) * 8];
    f16x8 b2 = *(const f16x8*)&hq[(2 * 64 + lane) * 8];

    LOADPAIR(p0, p1, k + 2)                   // depth-2 xg prefetch

    f32x4 acc0 = {0.f, 0.f, 0.f, 0.f}, acc1 = {0.f, 0.f, 0.f, 0.f};
    asm("v_mfma_f32_16x16x32_f16 %0, %1, %2, %0" : "+v"(acc0) : "a"(a00), "v"(b0));
    asm("v_mfma_f32_16x16x32_f16 %0, %1, %2, %0" : "+v"(acc1) : "a"(a10), "v"(b0));
    asm("v_mfma_f32_16x16x32_f16 %0, %1, %2, %0" : "+v"(acc0) : "a"(a01), "v"(b1));
    asm("v_mfma_f32_16x16x32_f16 %0, %1, %2, %0" : "+v"(acc1) : "a"(a11), "v"(b1));
    asm("v_mfma_f32_16x16x32_f16 %0, %1, %2, %0" : "+v"(acc0) : "a"(a02), "v"(b2));
    asm("v_mfma_f32_16x16x32_f16 %0, %1, %2, %0" : "+v"(acc1) : "a"(a12), "v"(b2));

    __fp16* hw = hfrag[(k & 1) ^ 1];
    if (k < SS){
      if (hA < HH){
        float gi = acc0.x + (float)cur0.x, gf = acc0.y + (float)cur0.y;
        float gg = acc0.z + (float)cur0.z, go = acc0.w + (float)cur0.w;
        cA = sigf(gf) * cA + sigf(gi) * tanhf_(gg);
        hw[wiA] = (__fp16)(sigf(go) * tanhf_(cA));
      }
      if (hB < HH){
        float gi = acc1.x + (float)cur1.x, gf = acc1.y + (float)cur1.y;
        float gg = acc1.z + (float)cur1.z, go = acc1.w + (float)cur1.w;
        cB = sigf(gf) * cB + sigf(gi) * tanhf_(gg);
        hw[wiB] = (__fp16)(sigf(go) * tanhf_(cB));
      }
    }
    if (k >= 1){
      if (rbA == 300){                       // feat rows 0..3 (wave 9, q=3)
        int ps = dir ? (SS - k) : (k - 1);
        float* fb = feats + ((size_t)ps * BB + bglob) * TT;
        float2 v01 = {acc0.x + (float)cur0.x + bo0, acc0.y + (float)cur0.y + bo1};
        float2 v23 = {acc0.z + (float)cur0.z + bo2, acc0.w + (float)cur0.w + bo3};
        *(float2*)fb = v01;
        *(float2*)(fb + 2) = v23;
      }
      if (rbB == 304){                       // feat rows 4..5 (wave 9, q=0)
        int ps = dir ? (SS - k) : (k - 1);
        float* fb = feats + ((size_t)ps * BB + bglob) * TT;
        float2 v45 = {acc1.x + (float)cur1.x + bo4, acc1.y + (float)cur1.y + bo5};
        *(float2*)(fb + 4) = v45;
      }
    }
    cur0 = nx0; cur1 = nx1; nx0 = p0; nx1 = p1;
    sync_lds();
  }
}

// ---------------- K3a: CRF chunked alpha-scan + gold partials ----------------
#define LOADSTAGE(X0,X1,X2,Y0,Y1,Y2, srow) do{ \
  int _r = (srow); if (_r >= SS) _r = 0; \
  const float2* _pF = (const float2*)(featsF + ((size_t)_r * BB + b) * TT); \
  const float2* _pB = (const float2*)(featsB + ((size_t)_r * BB + b) * TT); \
  X0 = _pF[0]; X1 = _pF[1]; X2 = _pF[2]; \
  Y0 = _pB[0]; Y1 = _pB[1]; Y2 = _pB[2]; }while(0)

#define ASTEP(X0,X1,X2,Y0,Y1,Y2, srow) do{ \
  float F0 = X0.x + Y0.x, F1 = X0.y + Y0.y, F2 = X1.x + Y1.x; \
  float F3 = X1.y + Y1.y, F4 = X2.x + Y2.x, F5 = X2.y + Y2.y; \
  float M = fmaxf(fmaxf(fmaxf(a0,a1),fmaxf(a2,a3)),fmaxf(a4,a5)); \
  float p01 = pk2(__expf(a0-M), __expf(a1-M)); \
  float p23 = pk2(__expf(a2-M), __expf(a3-M)); \
  float p45 = pk2(__expf(a4-M), __expf(a5-M)); \
  float s0 = dot2pk(p45, Tq2,  dot2pk(p23, Tq1,  dot2pk(p01, Tq0,  0.f))); \
  float s1 = dot2pk(p45, Tq5,  dot2pk(p23, Tq4,  dot2pk(p01, Tq3,  0.f))); \
  float s2 = dot2pk(p45, Tq8,  dot2pk(p23, Tq7,  dot2pk(p01, Tq6,  0.f))); \
  float s3 = dot2pk(p45, Tq11, dot2pk(p23, Tq10, dot2pk(p01, Tq9,  0.f))); \
  float s4 = dot2pk(p45, Tq14, dot2pk(p23, Tq13, dot2pk(p01, Tq12, 0.f))); \
  float s5 = dot2pk(p45, Tq17, dot2pk(p23, Tq16, dot2pk(p01, Tq15, 0.f))); \
  a0 = M + __logf(fmaxf(s0, 1e-37f)) + F0;  a1 = M + __logf(fmaxf(s1, 1e-37f)) + F1; \
  a2 = M + __logf(fmaxf(s2, 1e-37f)) + F2;  a3 = M + __logf(fmaxf(s3, 1e-37f)) + F3; \
  a4 = M + __logf(fmaxf(s4, 1e-37f)) + F4;  a5 = M + __logf(fmaxf(s5, 1e-37f)) + F5; \
  LOADSTAGE(X0,X1,X2,Y0,Y1,Y2, (srow) + 2); }while(0)

__global__ __launch_bounds__(256) void k_crf_scan(
    const float* __restrict__ featsF, const float* __restrict__ featsB,
    const float* __restrict__ trans, const int* __restrict__ tags,
    float* __restrict__ crfM, float* __restrict__ pgold){
  __shared__ float tr_sh[36];
  __shared__ u32 etp_sh[18];
  const int tid = threadIdx.x;
  if (tid < 36) tr_sh[tid] = trans[tid];
  if (tid < 18) etp_sh[tid] = __float_as_uint(
      pk2(__expf(trans[2 * tid]), __expf(trans[2 * tid + 1])));
  __syncthreads();
  const int bx = blockIdx.x;

  if (bx < 96){
    const int g = bx * 256 + tid;
    const int s0i = g % 6;
    const int c = (g / 6) % NCH;
    const int b = g / (6 * NCH);
    const int cbase = c * CHL;

    float Tq0=__int_as_float(etp_sh[0]),  Tq1=__int_as_float(etp_sh[1]),
          Tq2=__int_as_float(etp_sh[2]),  Tq3=__int_as_float(etp_sh[3]),
          Tq4=__int_as_float(etp_sh[4]),  Tq5=__int_as_float(etp_sh[5]),
          Tq6=__int_as_float(etp_sh[6]),  Tq7=__int_as_float(etp_sh[7]),
          Tq8=__int_as_float(etp_sh[8]),  Tq9=__int_as_float(etp_sh[9]),
          Tq10=__int_as_float(etp_sh[10]), Tq11=__int_as_float(etp_sh[11]),
          Tq12=__int_as_float(etp_sh[12]), Tq13=__int_as_float(etp_sh[13]),
          Tq14=__int_as_float(etp_sh[14]), Tq15=__int_as_float(etp_sh[15]),
          Tq16=__int_as_float(etp_sh[16]), Tq17=__int_as_float(etp_sh[17]);

    float a0 = (s0i == 0) ? 0.f : NEGV, a1 = (s0i == 1) ? 0.f : NEGV;
    float a2 = (s0i == 2) ? 0.f : NEGV, a3 = (s0i == 3) ? 0.f : NEGV;
    float a4 = (s0i == 4) ? 0.f : NEGV, a5 = (s0i == 5) ? 0.f : NEGV;

    float2 xA0,xA1,xA2,yA0,yA1,yA2, xB0,xB1,xB2,yB0,yB1,yB2;
    LOADSTAGE(xA0,xA1,xA2,yA0,yA1,yA2, cbase + 0);
    LOADSTAGE(xB0,xB1,xB2,yB0,yB1,yB2, cbase + 1);
    for (int s = 0; s < CHL; s += 2){
      ASTEP(xA0,xA1,xA2,yA0,yA1,yA2, cbase + s);
      ASTEP(xB0,xB1,xB2,yB0,yB1,yB2, cbase + s + 1);
    }
    float* mrow = crfM + ((size_t)(b * NCH + c) * 6 + s0i) * 6;
    mrow[0] = a0; mrow[1] = a1; mrow[2] = a2;
    mrow[3] = a3; mrow[4] = a4; mrow[5] = a5;
  } else {
    const int g2 = (bx - 96) * 256 + tid;
    const int b = g2 / NCH;
    const int c = g2 % NCH;
    const int* tg = tags + (size_t)b * SS + c * CHL;
    int prev = (c == 0) ? STARTT : tg[-1];
    float acc = 0.f;
    #pragma unroll 4
    for (int s = 0; s < CHL; ++s){
      int ct = tg[s];
      size_t fo = (size_t)(c * CHL + s) * BB * TT + (size_t)b * TT + ct;
      acc += tr_sh[ct * 6 + prev] + featsF[fo] + featsB[fo];
      prev = ct;
    }
    pgold[b * NCH + c] = acc;
  }
}

// ---------------- K3b: combine 16 chunk matrices + finish -------------------
__global__ __launch_bounds__(64) void k_crf_comb(
    const float* __restrict__ crfM, const float* __restrict__ pgold,
    const float* __restrict__ trans, const int* __restrict__ tags,
    float* __restrict__ out){
  const int b = blockIdx.x * 64 + threadIdx.x;
  float v0 = NEGV, v1 = NEGV, v2 = NEGV, v3 = NEGV, v4 = 0.f, v5 = NEGV;
  for (int c = 0; c < NCH; ++c){
    const float* mb = crfM + (size_t)(b * NCH + c) * 36;
    float n[6];
    #pragma unroll
    for (int j = 0; j < 6; ++j){
      float t0 = v0 + mb[0 * 6 + j], t1 = v1 + mb[1 * 6 + j];
      float t2 = v2 + mb[2 * 6 + j], t3 = v3 + mb[3 * 6 + j];
      float t4 = v4 + mb[4 * 6 + j], t5 = v5 + mb[5 * 6 + j];
      float m = fmaxf(fmaxf(fmaxf(t0,t1),fmaxf(t2,t3)),fmaxf(t4,t5));
      float s = __expf(t0-m)+__expf(t1-m)+__expf(t2-m)
              + __expf(t3-m)+__expf(t4-m)+__expf(t5-m);
      n[j] = m + __logf(s);
    }
    v0 = n[0]; v1 = n[1]; v2 = n[2]; v3 = n[3]; v4 = n[4]; v5 = n[5];
  }
  float z0 = v0 + trans[30], z1 = v1 + trans[31], z2 = v2 + trans[32];
  float z3 = v3 + trans[33], z4 = v4 + trans[34], z5 = v5 + trans[35];
  float M2 = fmaxf(fmaxf(fmaxf(z0,z1),fmaxf(z2,z3)),fmaxf(z4,z5));
  float ss = __expf(z0-M2)+__expf(z1-M2)+__expf(z2-M2)
           + __expf(z3-M2)+__expf(z4-M2)+__expf(z5-M2);
  float fwd = M2 + __logf(ss);

  float gold = trans[STOPT * 6 + tags[(size_t)b * SS + SS - 1]];
  #pragma unroll
  for (int c = 0; c < NCH; ++c) gold += pgold[b * NCH + c];
  out[b] = fwd - gold;
}

// ---------------- launch -----------------------------------------------------
extern "C" void kernel_launch(void* const* d_in, const int* in_sizes, int n_in,
                              void* d_out, int out_size, void* d_ws, size_t ws_size,
                              hipStream_t stream){
  const int*   sentence = (const int*)  d_in[0];
  const int*   tags     = (const int*)  d_in[1];
  const float* emb      = (const float*)d_in[2];
  const float* w_ih_f   = (const float*)d_in[3];
  const float* w_hh_f   = (const float*)d_in[4];
  const float* b_ih_f   = (const float*)d_in[5];
  const float* b_hh_f   = (const float*)d_in[6];
  const float* w_ih_b   = (const float*)d_in[7];
  const float* w_hh_b   = (const float*)d_in[8];
  const float* b_ih_b   = (const float*)d_in[9];
  const float* b_hh_b   = (const float*)d_in[10];
  const float* h0       = (const float*)d_in[11];
  const float* c0       = (const float*)d_in[12];
  const float* w_out    = (const float*)d_in[13];
  const float* b_out    = (const float*)d_in[14];
  const float* trans    = (const float*)d_in[15];
  float* out = (float*)d_out;

  __fp16* vxg  = (__fp16*)d_ws;                       // [2][8000][300] f16 (permuted)
  float* featsF = (float*)(vxg + (size_t)2 * VOCABN * G4);   // [512][256][6]
  float* featsB = featsF + (size_t)SS * BB * TT;      // [512][256][6]
  float* crfM   = featsB + (size_t)SS * BB * TT;      // [256][16][6][6]
  float* pgold  = crfM + (size_t)BB * NCH * 36;       // [256][16]

  k_gemm<<<2 * 125, 256, 0, stream>>>(emb, w_ih_f, w_ih_b,
                                      b_ih_f, b_hh_f, b_ih_b, b_hh_b, vxg);
  k_lstm<<<32, 640, 0, stream>>>(sentence, vxg, w_hh_f, w_hh_b, h0, c0, w_out, b_out,
                                 featsF, featsB);
  k_crf_scan<<<96 + 16, 256, 0, stream>>>(featsF, featsB, trans, tags, crfM, pgold);
  k_crf_comb<<<BB / 64, 64, 0, stream>>>(crfM, pgold, trans, tags, out);
}

// Round 15
// 503.562 us; speedup vs baseline: 1.1291x; 1.1291x over previous
//
#include <hip/hip_runtime.h>
#include <stdint.h>

#define VOCABN 8000
#define EE     300
#define HH     75
#define G4     300   // 4*H
#define TT     6
#define BB     256
#define SS     512
#define STARTT 4
#define STOPT  5
#define NEGV   (-10000.0f)
#define NCH    16    // CRF chunks
#define CHL    32    // steps per chunk

typedef __fp16 fp16x2 __attribute__((ext_vector_type(2)));
typedef __fp16 f16x8 __attribute__((ext_vector_type(8)));
typedef float f32x4 __attribute__((ext_vector_type(4)));
typedef unsigned int u32;

__device__ __forceinline__ float sigf(float x){
  return __builtin_amdgcn_rcpf(1.0f + __expf(-x));
}
__device__ __forceinline__ float tanhf_(float x){
  return __builtin_fmaf(__builtin_amdgcn_rcpf(1.0f + __expf(-2.0f * x)), 2.0f, -1.0f);
}
__device__ __forceinline__ float pk2(float a, float b){
  fp16x2 r = __builtin_amdgcn_cvt_pkrtz(a, b);
  return __builtin_bit_cast(float, r);
}
__device__ __forceinline__ float dot2pk(float a, float b, float c){
  asm("v_dot2_f32_f16 %0, %1, %2, %0" : "+v"(c) : "v"(a), "v"(b));
  return c;
}
// raw barrier: orders LDS, leaves global prefetches in flight
__device__ __forceinline__ void sync_lds(){
  __builtin_amdgcn_sched_barrier(0);
  asm volatile("s_waitcnt lgkmcnt(0)" ::: "memory");
  __builtin_amdgcn_s_barrier();
  __builtin_amdgcn_sched_barrier(0);
}

// ---------------- K1: vocab_xg[dir][v][g'] with PERMUTED gate order ----------
// Output col g is the permuted index; W rows loaded permuted so the output
// store is unit-stride. (r11 config — measured best.)
#define LDSR 20
__global__ __launch_bounds__(256) void k_gemm(
    const float* __restrict__ emb, const float* __restrict__ w_ih_f,
    const float* __restrict__ w_ih_b,
    const float* __restrict__ b_ih_f, const float* __restrict__ b_hh_f,
    const float* __restrict__ b_ih_b, const float* __restrict__ b_hh_b,
    float* __restrict__ vxg){
  __shared__ alignas(16) float a_sh[128 * LDSR];
  __shared__ alignas(16) float b_sh[64 * LDSR];
  __shared__ float bias_sh[64];
  const int bx = blockIdx.x;
  const int dir = bx / (63 * 5);
  const int rem = bx % (63 * 5);
  const int vt = rem / 5, gt = rem % 5;
  const int v0 = vt * 128, g0 = gt * 64;
  const int tid = threadIdx.x;
  const float* wdir = dir ? w_ih_b : w_ih_f;

  if (tid < 64){
    int g = g0 + tid;
    float bi = 0.f;
    if (g < G4){
      int gs = (g & 3) * 75 + (g >> 2);
      bi = dir ? (b_ih_b[gs] + b_hh_b[gs]) : (b_ih_f[gs] + b_hh_f[gs]);
    }
    bias_sh[tid] = bi;
  }

  float acc[8][4];
  #pragma unroll
  for (int i = 0; i < 8; ++i)
    #pragma unroll
    for (int j = 0; j < 4; ++j) acc[i][j] = 0.f;

  const int tx = tid & 15, ty = tid >> 4;
  const int la_r = tid >> 1, la_h = (tid & 1) * 8;
  const int lb_r = tid >> 2, lb_h = (tid & 3) * 4;

  const int va = v0 + la_r;
  const float* arow = emb + (size_t)(va < VOCABN ? va : 0) * EE;
  const int gb = g0 + lb_r;
  const int gsrc = (gb & 3) * 75 + (gb >> 2);
  const float* brow = wdir + (size_t)(gb < G4 ? gsrc : 0) * EE;
  const float4 z4 = {0.f, 0.f, 0.f, 0.f};

  for (int kk = 0; kk < 19; ++kk){
    const int e0 = kk * 16;
    float4 av0 = *(const float4*)&arow[e0 + la_h];
    float4 av1 = (e0 + la_h + 7 < EE) ? *(const float4*)&arow[e0 + la_h + 4] : z4;
    float4 bv  = (e0 + lb_h + 3 < EE) ? *(const float4*)&brow[e0 + lb_h]     : z4;
    __syncthreads();
    *(float4*)&a_sh[la_r * LDSR + la_h]     = av0;
    *(float4*)&a_sh[la_r * LDSR + la_h + 4] = av1;
    *(float4*)&b_sh[lb_r * LDSR + lb_h]     = bv;
    __syncthreads();
    #pragma unroll
    for (int e4 = 0; e4 < 4; ++e4){
      float4 bq[4], aq[8];
      #pragma unroll
      for (int j = 0; j < 4; ++j) bq[j] = *(const float4*)&b_sh[(tx + 16 * j) * LDSR + e4 * 4];
      #pragma unroll
      for (int i = 0; i < 8; ++i) aq[i] = *(const float4*)&a_sh[(ty + 16 * i) * LDSR + e4 * 4];
      #pragma unroll
      for (int i = 0; i < 8; ++i)
        #pragma unroll
        for (int j = 0; j < 4; ++j)
          acc[i][j] += aq[i].x * bq[j].x + aq[i].y * bq[j].y
                     + aq[i].z * bq[j].z + aq[i].w * bq[j].w;
    }
  }

  const size_t obase = (size_t)dir * VOCABN * G4;
  #pragma unroll
  for (int i = 0; i < 8; ++i){
    int v = v0 + ty + 16 * i;
    if (v < VOCABN){
      #pragma unroll
      for (int j = 0; j < 4; ++j){
        int g = g0 + tx + 16 * j;
        if (g < G4) vxg[obase + (size_t)v * G4 + g] = acc[i][j] + bias_sh[tx + 16 * j];
      }
    }
  }
}

// ---------------- K2: MFMA BiLSTM, 16 batch per block (r11 structure) --------
// h in MFMA B-FRAGMENT-ORDER LDS (conflict-free reads at byte addr lane*16).
// r14 tweak: accumulators INITIALIZED with the prefetched xg quad (same D-row
// mapping) — removes 8 dependent VALU adds from the barrier->ACT chain.
__global__ __launch_bounds__(640) void k_lstm(
    const int* __restrict__ sentence, const float* __restrict__ vxg,
    const float* __restrict__ w_hh_f, const float* __restrict__ w_hh_b,
    const float* __restrict__ h0, const float* __restrict__ c0,
    const float* __restrict__ w_out, const float* __restrict__ b_out,
    float* __restrict__ featsF, float* __restrict__ featsB){
  __shared__ int tok_sh[SS * 16];
  __shared__ alignas(16) __fp16 hfrag[2][12 * 16 * 8];   // [buf][k>>3][bb][k&7]
  const int bx = blockIdx.x;
  const int dir = bx >> 4, group = bx & 15;
  const int t = threadIdx.x;
  const int w = t >> 6, lane = t & 63;
  const int bb = lane & 15, q = lane >> 4;
  const int T0 = 2 * w, T1 = 2 * w + 1;
  const int rbA = 16 * T0 + 4 * q, rbB = 16 * T1 + 4 * q;
  const int hA = rbA >> 2, hB = rbB >> 2;      // hA = 8w+q, hB = 8w+4+q
  const int bglob = group * 16 + bb;
  const int wiA = w * 128 + bb * 8 + q;        // fragment-order write indices
  const int wiB = w * 128 + bb * 8 + 4 + q;

  for (int i = t; i < 2 * 12 * 16 * 4; i += 640) ((u32*)hfrag)[i] = 0;
  for (int i = t; i < 16 * SS; i += 640){
    int bq = i >> 9, s = i & 511;
    tok_sh[s * 16 + ((bq + s) & 15)] = sentence[(size_t)(group * 16 + bq) * SS + s];
  }
  __syncthreads();

  const float* whh = dir ? w_hh_b : w_hh_f;
  f16x8 a00, a01, a02, a10, a11, a12;
  #define BUILD_A(dst, T, c) { \
    int m = 16 * (T) + bb; int kb = 32 * (c) + 8 * q; \
    _Pragma("unroll") \
    for (int j = 0; j < 8; ++j){ \
      int kk = kb + j; float wv = 0.f; \
      if (kk < HH){ \
        if (m < 300) wv = whh[((m & 3) * 75 + (m >> 2)) * HH + kk]; \
        else if (m < 306) wv = w_out[(m - 300) * (2 * HH) + dir * HH + kk]; \
      } \
      dst[j] = (__fp16)wv; } }
  BUILD_A(a00, T0, 0) BUILD_A(a01, T0, 1) BUILD_A(a02, T0, 2)
  BUILD_A(a10, T1, 0) BUILD_A(a11, T1, 1) BUILD_A(a12, T1, 2)

  float cA = 0.f, cB = 0.f;
  if (hA < HH){
    cA = c0[((size_t)dir * BB + bglob) * HH + hA];
    hfrag[0][wiA] = (__fp16)h0[((size_t)dir * BB + bglob) * HH + hA];
  }
  if (hB < HH){
    cB = c0[((size_t)dir * BB + bglob) * HH + hB];
    hfrag[0][wiB] = (__fp16)h0[((size_t)dir * BB + bglob) * HH + hB];
  }
  const float bo0 = dir ? 0.f : b_out[0], bo1 = dir ? 0.f : b_out[1];
  const float bo2 = dir ? 0.f : b_out[2], bo3 = dir ? 0.f : b_out[3];
  const float bo4 = dir ? 0.f : b_out[4], bo5 = dir ? 0.f : b_out[5];
  __syncthreads();

  const float* vx = vxg + (size_t)dir * VOCABN * G4;
  float* feats = dir ? featsB : featsF;
  const float4 zf4 = {0.f, 0.f, 0.f, 0.f};

  float4 cur0 = zf4, cur1 = zf4, nx0 = zf4, nx1 = zf4;
  {
    int p = dir ? (SS - 1) : 0;
    int tk = tok_sh[p * 16 + ((bb + p) & 15)];
    const float* base = vx + (size_t)tk * G4;
    if (hA < HH) cur0 = *(const float4*)(base + rbA);
    if (hB < HH) cur1 = *(const float4*)(base + rbB);
    p = dir ? (SS - 2) : 1;
    tk = tok_sh[p * 16 + ((bb + p) & 15)];
    base = vx + (size_t)tk * G4;
    if (hA < HH) nx0 = *(const float4*)(base + rbA);
    if (hB < HH) nx1 = *(const float4*)(base + rbB);
  }

  for (int k = 0; k <= SS; ++k){
    const __fp16* hq = hfrag[k & 1];
    f16x8 b0 = *(const f16x8*)&hq[(0 * 64 + lane) * 8];   // byte addr = lane*16
    f16x8 b1 = *(const f16x8*)&hq[(1 * 64 + lane) * 8];
    f16x8 b2 = *(const f16x8*)&hq[(2 * 64 + lane) * 8];

    float4 p0 = zf4, p1 = zf4;
    if (k + 2 < SS){                        // depth-2 xg prefetch
      int p = dir ? (SS - 3 - k) : (k + 2);
      int tk = tok_sh[p * 16 + ((bb + p) & 15)];
      const float* base = vx + (size_t)tk * G4;
      if (hA < HH) p0 = *(const float4*)(base + rbA);
      if (hB < HH) p1 = *(const float4*)(base + rbB);
    }

    // acc initialized with xg quad (C-operand is free in MFMA; shortens the
    // post-MFMA dependent chain by 4 adds per tile)
    f32x4 acc0 = {cur0.x, cur0.y, cur0.z, cur0.w};
    f32x4 acc1 = {cur1.x, cur1.y, cur1.z, cur1.w};
    asm("v_mfma_f32_16x16x32_f16 %0, %1, %2, %0" : "+v"(acc0) : "a"(a00), "v"(b0));
    asm("v_mfma_f32_16x16x32_f16 %0, %1, %2, %0" : "+v"(acc1) : "a"(a10), "v"(b0));
    asm("v_mfma_f32_16x16x32_f16 %0, %1, %2, %0" : "+v"(acc0) : "a"(a01), "v"(b1));
    asm("v_mfma_f32_16x16x32_f16 %0, %1, %2, %0" : "+v"(acc1) : "a"(a11), "v"(b1));
    asm("v_mfma_f32_16x16x32_f16 %0, %1, %2, %0" : "+v"(acc0) : "a"(a02), "v"(b2));
    asm("v_mfma_f32_16x16x32_f16 %0, %1, %2, %0" : "+v"(acc1) : "a"(a12), "v"(b2));

    __fp16* hw = hfrag[(k & 1) ^ 1];
    if (k < SS){
      if (hA < HH){
        float gi = acc0.x, gf = acc0.y, gg = acc0.z, go = acc0.w;
        cA = sigf(gf) * cA + sigf(gi) * tanhf_(gg);
        hw[wiA] = (__fp16)(sigf(go) * tanhf_(cA));
      }
      if (hB < HH){
        float gi = acc1.x, gf = acc1.y, gg = acc1.z, go = acc1.w;
        cB = sigf(gf) * cB + sigf(gi) * tanhf_(gg);
        hw[wiB] = (__fp16)(sigf(go) * tanhf_(cB));
      }
    }
    if (k >= 1){
      if (rbA == 300){                       // feat rows 0..3 (wave 9, q=3)
        int ps = dir ? (SS - k) : (k - 1);
        float* fb = feats + ((size_t)ps * BB + bglob) * TT;
        float2 v01 = {acc0.x + bo0, acc0.y + bo1};
        float2 v23 = {acc0.z + bo2, acc0.w + bo3};
        *(float2*)fb = v01;
        *(float2*)(fb + 2) = v23;
      }
      if (rbB == 304){                       // feat rows 4..5 (wave 9, q=0)
        int ps = dir ? (SS - k) : (k - 1);
        float* fb = feats + ((size_t)ps * BB + bglob) * TT;
        float2 v45 = {acc1.x + bo4, acc1.y + bo5};
        *(float2*)(fb + 4) = v45;
      }
    }
    cur0 = nx0; cur1 = nx1; nx0 = p0; nx1 = p1;
    sync_lds();
  }
}

// ---------------- K3a: CRF chunked alpha-scan + gold partials ----------------
#define LOADSTAGE(X0,X1,X2,Y0,Y1,Y2, srow) do{ \
  int _r = (srow); if (_r >= SS) _r = 0; \
  const float2* _pF = (const float2*)(featsF + ((size_t)_r * BB + b) * TT); \
  const float2* _pB = (const float2*)(featsB + ((size_t)_r * BB + b) * TT); \
  X0 = _pF[0]; X1 = _pF[1]; X2 = _pF[2]; \
  Y0 = _pB[0]; Y1 = _pB[1]; Y2 = _pB[2]; }while(0)

#define ASTEP(X0,X1,X2,Y0,Y1,Y2, srow) do{ \
  float F0 = X0.x + Y0.x, F1 = X0.y + Y0.y, F2 = X1.x + Y1.x; \
  float F3 = X1.y + Y1.y, F4 = X2.x + Y2.x, F5 = X2.y + Y2.y; \
  float M = fmaxf(fmaxf(fmaxf(a0,a1),fmaxf(a2,a3)),fmaxf(a4,a5)); \
  float p01 = pk2(__expf(a0-M), __expf(a1-M)); \
  float p23 = pk2(__expf(a2-M), __expf(a3-M)); \
  float p45 = pk2(__expf(a4-M), __expf(a5-M)); \
  float s0 = dot2pk(p45, Tq2,  dot2pk(p23, Tq1,  dot2pk(p01, Tq0,  0.f))); \
  float s1 = dot2pk(p45, Tq5,  dot2pk(p23, Tq4,  dot2pk(p01, Tq3,  0.f))); \
  float s2 = dot2pk(p45, Tq8,  dot2pk(p23, Tq7,  dot2pk(p01, Tq6,  0.f))); \
  float s3 = dot2pk(p45, Tq11, dot2pk(p23, Tq10, dot2pk(p01, Tq9,  0.f))); \
  float s4 = dot2pk(p45, Tq14, dot2pk(p23, Tq13, dot2pk(p01, Tq12, 0.f))); \
  float s5 = dot2pk(p45, Tq17, dot2pk(p23, Tq16, dot2pk(p01, Tq15, 0.f))); \
  a0 = M + __logf(fmaxf(s0, 1e-37f)) + F0;  a1 = M + __logf(fmaxf(s1, 1e-37f)) + F1; \
  a2 = M + __logf(fmaxf(s2, 1e-37f)) + F2;  a3 = M + __logf(fmaxf(s3, 1e-37f)) + F3; \
  a4 = M + __logf(fmaxf(s4, 1e-37f)) + F4;  a5 = M + __logf(fmaxf(s5, 1e-37f)) + F5; \
  LOADSTAGE(X0,X1,X2,Y0,Y1,Y2, (srow) + 2); }while(0)

__global__ __launch_bounds__(256) void k_crf_scan(
    const float* __restrict__ featsF, const float* __restrict__ featsB,
    const float* __restrict__ trans, const int* __restrict__ tags,
    float* __restrict__ crfM, float* __restrict__ pgold){
  __shared__ float tr_sh[36];
  __shared__ u32 etp_sh[18];
  const int tid = threadIdx.x;
  if (tid < 36) tr_sh[tid] = trans[tid];
  if (tid < 18) etp_sh[tid] = __float_as_uint(
      pk2(__expf(trans[2 * tid]), __expf(trans[2 * tid + 1])));
  __syncthreads();
  const int bx = blockIdx.x;

  if (bx < 96){
    const int g = bx * 256 + tid;
    const int s0i = g % 6;
    const int c = (g / 6) % NCH;
    const int b = g / (6 * NCH);
    const int cbase = c * CHL;

    float Tq0=__int_as_float(etp_sh[0]),  Tq1=__int_as_float(etp_sh[1]),
          Tq2=__int_as_float(etp_sh[2]),  Tq3=__int_as_float(etp_sh[3]),
          Tq4=__int_as_float(etp_sh[4]),  Tq5=__int_as_float(etp_sh[5]),
          Tq6=__int_as_float(etp_sh[6]),  Tq7=__int_as_float(etp_sh[7]),
          Tq8=__int_as_float(etp_sh[8]),  Tq9=__int_as_float(etp_sh[9]),
          Tq10=__int_as_float(etp_sh[10]), Tq11=__int_as_float(etp_sh[11]),
          Tq12=__int_as_float(etp_sh[12]), Tq13=__int_as_float(etp_sh[13]),
          Tq14=__int_as_float(etp_sh[14]), Tq15=__int_as_float(etp_sh[15]),
          Tq16=__int_as_float(etp_sh[16]), Tq17=__int_as_float(etp_sh[17]);

    float a0 = (s0i == 0) ? 0.f : NEGV, a1 = (s0i == 1) ? 0.f : NEGV;
    float a2 = (s0i == 2) ? 0.f : NEGV, a3 = (s0i == 3) ? 0.f : NEGV;
    float a4 = (s0i == 4) ? 0.f : NEGV, a5 = (s0i == 5) ? 0.f : NEGV;

    float2 xA0,xA1,xA2,yA0,yA1,yA2, xB0,xB1,xB2,yB0,yB1,yB2;
    LOADSTAGE(xA0,xA1,xA2,yA0,yA1,yA2, cbase + 0);
    LOADSTAGE(xB0,xB1,xB2,yB0,yB1,yB2, cbase + 1);
    for (int s = 0; s < CHL; s += 2){
      ASTEP(xA0,xA1,xA2,yA0,yA1,yA2, cbase + s);
      ASTEP(xB0,xB1,xB2,yB0,yB1,yB2, cbase + s + 1);
    }
    float* mrow = crfM + ((size_t)(b * NCH + c) * 6 + s0i) * 6;
    mrow[0] = a0; mrow[1] = a1; mrow[2] = a2;
    mrow[3] = a3; mrow[4] = a4; mrow[5] = a5;
  } else {
    const int g2 = (bx - 96) * 256 + tid;
    const int b = g2 / NCH;
    const int c = g2 % NCH;
    const int* tg = tags + (size_t)b * SS + c * CHL;
    int prev = (c == 0) ? STARTT : tg[-1];
    float acc = 0.f;
    #pragma unroll 4
    for (int s = 0; s < CHL; ++s){
      int ct = tg[s];
      size_t fo = (size_t)(c * CHL + s) * BB * TT + (size_t)b * TT + ct;
      acc += tr_sh[ct * 6 + prev] + featsF[fo] + featsB[fo];
      prev = ct;
    }
    pgold[b * NCH + c] = acc;
  }
}

// ---------------- K3b: combine 16 chunk matrices + finish -------------------
__global__ __launch_bounds__(64) void k_crf_comb(
    const float* __restrict__ crfM, const float* __restrict__ pgold,
    const float* __restrict__ trans, const int* __restrict__ tags,
    float* __restrict__ out){
  const int b = blockIdx.x * 64 + threadIdx.x;
  float v0 = NEGV, v1 = NEGV, v2 = NEGV, v3 = NEGV, v4 = 0.f, v5 = NEGV;
  for (int c = 0; c < NCH; ++c){
    const float* mb = crfM + (size_t)(b * NCH + c) * 36;
    float n[6];
    #pragma unroll
    for (int j = 0; j < 6; ++j){
      float t0 = v0 + mb[0 * 6 + j], t1 = v1 + mb[1 * 6 + j];
      float t2 = v2 + mb[2 * 6 + j], t3 = v3 + mb[3 * 6 + j];
      float t4 = v4 + mb[4 * 6 + j], t5 = v5 + mb[5 * 6 + j];
      float m = fmaxf(fmaxf(fmaxf(t0,t1),fmaxf(t2,t3)),fmaxf(t4,t5));
      float s = __expf(t0-m)+__expf(t1-m)+__expf(t2-m)
              + __expf(t3-m)+__expf(t4-m)+__expf(t5-m);
      n[j] = m + __logf(s);
    }
    v0 = n[0]; v1 = n[1]; v2 = n[2]; v3 = n[3]; v4 = n[4]; v5 = n[5];
  }
  float z0 = v0 + trans[30], z1 = v1 + trans[31], z2 = v2 + trans[32];
  float z3 = v3 + trans[33], z4 = v4 + trans[34], z5 = v5 + trans[35];
  float M2 = fmaxf(fmaxf(fmaxf(z0,z1),fmaxf(z2,z3)),fmaxf(z4,z5));
  float ss = __expf(z0-M2)+__expf(z1-M2)+__expf(z2-M2)
           + __expf(z3-M2)+__expf(z4-M2)+__expf(z5-M2);
  float fwd = M2 + __logf(ss);

  float gold = trans[STOPT * 6 + tags[(size_t)b * SS + SS - 1]];
  #pragma unroll
  for (int c = 0; c < NCH; ++c) gold += pgold[b * NCH + c];
  out[b] = fwd - gold;
}

// ---------------- launch -----------------------------------------------------
extern "C" void kernel_launch(void* const* d_in, const int* in_sizes, int n_in,
                              void* d_out, int out_size, void* d_ws, size_t ws_size,
                              hipStream_t stream){
  const int*   sentence = (const int*)  d_in[0];
  const int*   tags     = (const int*)  d_in[1];
  const float* emb      = (const float*)d_in[2];
  const float* w_ih_f   = (const float*)d_in[3];
  const float* w_hh_f   = (const float*)d_in[4];
  const float* b_ih_f   = (const float*)d_in[5];
  const float* b_hh_f   = (const float*)d_in[6];
  const float* w_ih_b   = (const float*)d_in[7];
  const float* w_hh_b   = (const float*)d_in[8];
  const float* b_ih_b   = (const float*)d_in[9];
  const float* b_hh_b   = (const float*)d_in[10];
  const float* h0       = (const float*)d_in[11];
  const float* c0       = (const float*)d_in[12];
  const float* w_out    = (const float*)d_in[13];
  const float* b_out    = (const float*)d_in[14];
  const float* trans    = (const float*)d_in[15];
  float* out = (float*)d_out;

  float* ws = (float*)d_ws;
  float* vxg    = ws;                                 // [2][8000][300] (permuted)
  float* featsF = vxg + (size_t)2 * VOCABN * G4;      // [512][256][6]
  float* featsB = featsF + (size_t)SS * BB * TT;      // [512][256][6]
  float* crfM   = featsB + (size_t)SS * BB * TT;      // [256][16][6][6]
  float* pgold  = crfM + (size_t)BB * NCH * 36;       // [256][16]

  k_gemm<<<2 * 63 * 5, 256, 0, stream>>>(emb, w_ih_f, w_ih_b,
                                         b_ih_f, b_hh_f, b_ih_b, b_hh_b, vxg);
  k_lstm<<<32, 640, 0, stream>>>(sentence, vxg, w_hh_f, w_hh_b, h0, c0, w_out, b_out,
                                 featsF, featsB);
  k_crf_scan<<<96 + 16, 256, 0, stream>>>(featsF, featsB, trans, tags, crfM, pgold);
  k_crf_comb<<<BB / 64, 64, 0, stream>>>(crfM, pgold, trans, tags, out);
}

// Round 16
// 459.065 us; speedup vs baseline: 1.2385x; 1.0969x over previous
//
#include <hip/hip_runtime.h>
#include <stdint.h>

#define VOCABN 8000
#define EE     300
#define HH     75
#define G4     300   // 4*H
#define TT     6
#define BB     256
#define SS     512
#define STARTT 4
#define STOPT  5
#define NEGV   (-10000.0f)
#define NCH    16    // CRF chunks
#define CHL    32    // steps per chunk

typedef __fp16 fp16x2 __attribute__((ext_vector_type(2)));
typedef __fp16 f16x8 __attribute__((ext_vector_type(8)));
typedef float f32x4 __attribute__((ext_vector_type(4)));
typedef unsigned int u32;

__device__ __forceinline__ float sigf(float x){
  return __builtin_amdgcn_rcpf(1.0f + __expf(-x));
}
__device__ __forceinline__ float tanhf_(float x){
  return __builtin_fmaf(__builtin_amdgcn_rcpf(1.0f + __expf(-2.0f * x)), 2.0f, -1.0f);
}
__device__ __forceinline__ float pk2(float a, float b){
  fp16x2 r = __builtin_amdgcn_cvt_pkrtz(a, b);
  return __builtin_bit_cast(float, r);
}
__device__ __forceinline__ float dot2pk(float a, float b, float c){
  asm("v_dot2_f32_f16 %0, %1, %2, %0" : "+v"(c) : "v"(a), "v"(b));
  return c;
}
// raw barrier: orders LDS, leaves global prefetches in flight
__device__ __forceinline__ void sync_lds(){
  __builtin_amdgcn_sched_barrier(0);
  asm volatile("s_waitcnt lgkmcnt(0)" ::: "memory");
  __builtin_amdgcn_s_barrier();
  __builtin_amdgcn_sched_barrier(0);
}

// ---------------- K1: MFMA f16 GEMM -> vxg[dir][v][g'] (permuted, f32 out) ---
// Mapping validated in r14 (passed absmax 8.0): A lane(q,bb) row=bb k=8q+j,
// D row=4q+r col=bb. r15 fix: COALESCED B-staging (8 thr/row float4 loads ->
// cvt_pkrtz -> fragment-order LDS), replacing r14's ~10K scalar loads/chunk.
__global__ __launch_bounds__(256) void k_gemm(
    const float* __restrict__ emb, const float* __restrict__ w_ih_f,
    const float* __restrict__ w_ih_b,
    const float* __restrict__ b_ih_f, const float* __restrict__ b_hh_f,
    const float* __restrict__ b_ih_b, const float* __restrict__ b_hh_b,
    float* __restrict__ vxg){
  __shared__ alignas(16) __fp16 bfrag[19 * 64 * 8];   // [gtile][lane][j]
  __shared__ float bias_sh[304];
  const int bx = blockIdx.x;
  const int dir = bx / 125;
  const int vblk = bx % 125;
  const int v0 = vblk * 64;
  const int tid = threadIdx.x;
  const int w = tid >> 6, lane = tid & 63;
  const int bb = lane & 15, q = lane >> 4;
  const float* wdir = dir ? w_ih_b : w_ih_f;

  for (int g = tid; g < 304; g += 256){
    float bi = 0.f;
    if (g < G4){
      int gs = (g & 3) * 75 + (g >> 2);
      bi = dir ? (b_ih_b[gs] + b_hh_b[gs]) : (b_ih_f[gs] + b_hh_f[gs]);
    }
    bias_sh[g] = bi;
  }
  // zero the 4 never-staged B rows (g 300..303, tile 18 cols 12..15) once
  if (tid < 16){
    int col = 12 + (tid & 3), qq = tid >> 2;
    *(u32*)&bfrag[(18 * 64 + qq * 16 + col) * 8]     = 0;
    *(u32*)&bfrag[(18 * 64 + qq * 16 + col) * 8 + 2] = 0;
    *(u32*)&bfrag[(18 * 64 + qq * 16 + col) * 8 + 4] = 0;
    *(u32*)&bfrag[(18 * 64 + qq * 16 + col) * 8 + 6] = 0;
  }

  f32x4 acc[19];
  #pragma unroll
  for (int t = 0; t < 19; ++t) acc[t] = (f32x4){0.f, 0.f, 0.f, 0.f};

  const float* arow = emb + (size_t)(v0 + 16 * w + bb) * EE;
  const int rstage = tid >> 3;      // g-row this thread helps stage
  const int sub = tid & 7;          // float4 slot within the 32-wide chunk

  for (int c = 0; c < 10; ++c){
    // ---- A fragment (global f32 -> f16x8), rows are v = v0+16w+bb ----
    f16x8 afrag;
    const int kb = 32 * c + 8 * q;
    if (c < 9){
      float4 x0 = *(const float4*)(arow + kb);
      float4 x1 = *(const float4*)(arow + kb + 4);
      afrag[0] = (__fp16)x0.x; afrag[1] = (__fp16)x0.y;
      afrag[2] = (__fp16)x0.z; afrag[3] = (__fp16)x0.w;
      afrag[4] = (__fp16)x1.x; afrag[5] = (__fp16)x1.y;
      afrag[6] = (__fp16)x1.z; afrag[7] = (__fp16)x1.w;
    } else {
      #pragma unroll
      for (int j = 0; j < 8; ++j)
        afrag[j] = (kb + j < EE) ? (__fp16)arow[kb + j] : (__fp16)0.f;
    }

    // ---- stage B chunk, COALESCED: 8 threads per g-row, float4 each ----
    __syncthreads();   // protect bfrag reuse from previous chunk's MFMAs
    for (int r0 = 0; r0 < 300; r0 += 32){
      int r = r0 + rstage;
      if (r < 300){
        int gsrc2 = (r & 3) * 75 + (r >> 2);
        const float* wr = wdir + (size_t)gsrc2 * EE;
        int e0 = 32 * c + 4 * sub;
        float4 xv;
        if (e0 + 3 < EE) xv = *(const float4*)(wr + e0);
        else {
          xv.x = (e0     < EE) ? wr[e0]     : 0.f;
          xv.y = (e0 + 1 < EE) ? wr[e0 + 1] : 0.f;
          xv.z = (e0 + 2 < EE) ? wr[e0 + 2] : 0.f;
          xv.w = (e0 + 3 < EE) ? wr[e0 + 3] : 0.f;
        }
        fp16x2 lo = __builtin_amdgcn_cvt_pkrtz(xv.x, xv.y);
        fp16x2 hi = __builtin_amdgcn_cvt_pkrtz(xv.z, xv.w);
        int t2 = r >> 4, col = r & 15;
        int qq = sub >> 1, j = 4 * (sub & 1);
        u32* dst = (u32*)&bfrag[(t2 * 64 + qq * 16 + col) * 8 + j];
        dst[0] = __builtin_bit_cast(u32, lo);
        dst[1] = __builtin_bit_cast(u32, hi);
      }
    }
    __syncthreads();

    // ---- 19 MFMAs against the staged chunk ----
    #pragma unroll
    for (int t = 0; t < 19; ++t){
      f16x8 bf = *(const f16x8*)&bfrag[(t * 64 + lane) * 8];
      asm("v_mfma_f32_16x16x32_f16 %0, %1, %2, %0"
          : "+v"(acc[t]) : "v"(afrag), "v"(bf));
    }
  }

  const size_t obase = (size_t)dir * VOCABN * G4;
  #pragma unroll
  for (int t = 0; t < 19; ++t){
    int g = 16 * t + bb;
    if (g < G4){
      float bi = bias_sh[g];
      #pragma unroll
      for (int r = 0; r < 4; ++r){
        int v = v0 + 16 * w + 4 * q + r;
        vxg[obase + (size_t)v * G4 + g] = acc[t][r] + bi;
      }
    }
  }
}

// ---------------- K2: MFMA BiLSTM, 16 batch per block (r15, FROZEN) ----------
__global__ __launch_bounds__(640) void k_lstm(
    const int* __restrict__ sentence, const float* __restrict__ vxg,
    const float* __restrict__ w_hh_f, const float* __restrict__ w_hh_b,
    const float* __restrict__ h0, const float* __restrict__ c0,
    const float* __restrict__ w_out, const float* __restrict__ b_out,
    float* __restrict__ featsF, float* __restrict__ featsB){
  __shared__ int tok_sh[SS * 16];
  __shared__ alignas(16) __fp16 hfrag[2][12 * 16 * 8];   // [buf][k>>3][bb][k&7]
  const int bx = blockIdx.x;
  const int dir = bx >> 4, group = bx & 15;
  const int t = threadIdx.x;
  const int w = t >> 6, lane = t & 63;
  const int bb = lane & 15, q = lane >> 4;
  const int T0 = 2 * w, T1 = 2 * w + 1;
  const int rbA = 16 * T0 + 4 * q, rbB = 16 * T1 + 4 * q;
  const int hA = rbA >> 2, hB = rbB >> 2;      // hA = 8w+q, hB = 8w+4+q
  const int bglob = group * 16 + bb;
  const int wiA = w * 128 + bb * 8 + q;        // fragment-order write indices
  const int wiB = w * 128 + bb * 8 + 4 + q;

  for (int i = t; i < 2 * 12 * 16 * 4; i += 640) ((u32*)hfrag)[i] = 0;
  for (int i = t; i < 16 * SS; i += 640){
    int bq = i >> 9, s = i & 511;
    tok_sh[s * 16 + ((bq + s) & 15)] = sentence[(size_t)(group * 16 + bq) * SS + s];
  }
  __syncthreads();

  const float* whh = dir ? w_hh_b : w_hh_f;
  f16x8 a00, a01, a02, a10, a11, a12;
  #define BUILD_A(dst, T, c) { \
    int m = 16 * (T) + bb; int kb = 32 * (c) + 8 * q; \
    _Pragma("unroll") \
    for (int j = 0; j < 8; ++j){ \
      int kk = kb + j; float wv = 0.f; \
      if (kk < HH){ \
        if (m < 300) wv = whh[((m & 3) * 75 + (m >> 2)) * HH + kk]; \
        else if (m < 306) wv = w_out[(m - 300) * (2 * HH) + dir * HH + kk]; \
      } \
      dst[j] = (__fp16)wv; } }
  BUILD_A(a00, T0, 0) BUILD_A(a01, T0, 1) BUILD_A(a02, T0, 2)
  BUILD_A(a10, T1, 0) BUILD_A(a11, T1, 1) BUILD_A(a12, T1, 2)

  float cA = 0.f, cB = 0.f;
  if (hA < HH){
    cA = c0[((size_t)dir * BB + bglob) * HH + hA];
    hfrag[0][wiA] = (__fp16)h0[((size_t)dir * BB + bglob) * HH + hA];
  }
  if (hB < HH){
    cB = c0[((size_t)dir * BB + bglob) * HH + hB];
    hfrag[0][wiB] = (__fp16)h0[((size_t)dir * BB + bglob) * HH + hB];
  }
  const float bo0 = dir ? 0.f : b_out[0], bo1 = dir ? 0.f : b_out[1];
  const float bo2 = dir ? 0.f : b_out[2], bo3 = dir ? 0.f : b_out[3];
  const float bo4 = dir ? 0.f : b_out[4], bo5 = dir ? 0.f : b_out[5];
  __syncthreads();

  const float* vx = vxg + (size_t)dir * VOCABN * G4;
  float* feats = dir ? featsB : featsF;
  const float4 zf4 = {0.f, 0.f, 0.f, 0.f};

  float4 cur0 = zf4, cur1 = zf4, nx0 = zf4, nx1 = zf4;
  {
    int p = dir ? (SS - 1) : 0;
    int tk = tok_sh[p * 16 + ((bb + p) & 15)];
    const float* base = vx + (size_t)tk * G4;
    if (hA < HH) cur0 = *(const float4*)(base + rbA);
    if (hB < HH) cur1 = *(const float4*)(base + rbB);
    p = dir ? (SS - 2) : 1;
    tk = tok_sh[p * 16 + ((bb + p) & 15)];
    base = vx + (size_t)tk * G4;
    if (hA < HH) nx0 = *(const float4*)(base + rbA);
    if (hB < HH) nx1 = *(const float4*)(base + rbB);
  }

  for (int k = 0; k <= SS; ++k){
    const __fp16* hq = hfrag[k & 1];
    f16x8 b0 = *(const f16x8*)&hq[(0 * 64 + lane) * 8];   // byte addr = lane*16
    f16x8 b1 = *(const f16x8*)&hq[(1 * 64 + lane) * 8];
    f16x8 b2 = *(const f16x8*)&hq[(2 * 64 + lane) * 8];

    float4 p0 = zf4, p1 = zf4;
    if (k + 2 < SS){                        // depth-2 xg prefetch
      int p = dir ? (SS - 3 - k) : (k + 2);
      int tk = tok_sh[p * 16 + ((bb + p) & 15)];
      const float* base = vx + (size_t)tk * G4;
      if (hA < HH) p0 = *(const float4*)(base + rbA);
      if (hB < HH) p1 = *(const float4*)(base + rbB);
    }

    // acc initialized with xg quad (C-operand is free in MFMA)
    f32x4 acc0 = {cur0.x, cur0.y, cur0.z, cur0.w};
    f32x4 acc1 = {cur1.x, cur1.y, cur1.z, cur1.w};
    asm("v_mfma_f32_16x16x32_f16 %0, %1, %2, %0" : "+v"(acc0) : "a"(a00), "v"(b0));
    asm("v_mfma_f32_16x16x32_f16 %0, %1, %2, %0" : "+v"(acc1) : "a"(a10), "v"(b0));
    asm("v_mfma_f32_16x16x32_f16 %0, %1, %2, %0" : "+v"(acc0) : "a"(a01), "v"(b1));
    asm("v_mfma_f32_16x16x32_f16 %0, %1, %2, %0" : "+v"(acc1) : "a"(a11), "v"(b1));
    asm("v_mfma_f32_16x16x32_f16 %0, %1, %2, %0" : "+v"(acc0) : "a"(a02), "v"(b2));
    asm("v_mfma_f32_16x16x32_f16 %0, %1, %2, %0" : "+v"(acc1) : "a"(a12), "v"(b2));

    __fp16* hw = hfrag[(k & 1) ^ 1];
    if (k < SS){
      if (hA < HH){
        float gi = acc0.x, gf = acc0.y, gg = acc0.z, go = acc0.w;
        cA = sigf(gf) * cA + sigf(gi) * tanhf_(gg);
        hw[wiA] = (__fp16)(sigf(go) * tanhf_(cA));
      }
      if (hB < HH){
        float gi = acc1.x, gf = acc1.y, gg = acc1.z, go = acc1.w;
        cB = sigf(gf) * cB + sigf(gi) * tanhf_(gg);
        hw[wiB] = (__fp16)(sigf(go) * tanhf_(cB));
      }
    }
    if (k >= 1){
      if (rbA == 300){                       // feat rows 0..3 (wave 9, q=3)
        int ps = dir ? (SS - k) : (k - 1);
        float* fb = feats + ((size_t)ps * BB + bglob) * TT;
        float2 v01 = {acc0.x + bo0, acc0.y + bo1};
        float2 v23 = {acc0.z + bo2, acc0.w + bo3};
        *(float2*)fb = v01;
        *(float2*)(fb + 2) = v23;
      }
      if (rbB == 304){                       // feat rows 4..5 (wave 9, q=0)
        int ps = dir ? (SS - k) : (k - 1);
        float* fb = feats + ((size_t)ps * BB + bglob) * TT;
        float2 v45 = {acc1.x + bo4, acc1.y + bo5};
        *(float2*)(fb + 4) = v45;
      }
    }
    cur0 = nx0; cur1 = nx1; nx0 = p0; nx1 = p1;
    sync_lds();
  }
}

// ---------------- K3a: CRF chunked alpha-scan + gold partials ----------------
#define LOADSTAGE(X0,X1,X2,Y0,Y1,Y2, srow) do{ \
  int _r = (srow); if (_r >= SS) _r = 0; \
  const float2* _pF = (const float2*)(featsF + ((size_t)_r * BB + b) * TT); \
  const float2* _pB = (const float2*)(featsB + ((size_t)_r * BB + b) * TT); \
  X0 = _pF[0]; X1 = _pF[1]; X2 = _pF[2]; \
  Y0 = _pB[0]; Y1 = _pB[1]; Y2 = _pB[2]; }while(0)

#define ASTEP(X0,X1,X2,Y0,Y1,Y2, srow) do{ \
  float F0 = X0.x + Y0.x, F1 = X0.y + Y0.y, F2 = X1.x + Y1.x; \
  float F3 = X1.y + Y1.y, F4 = X2.x + Y2.x, F5 = X2.y + Y2.y; \
  float M = fmaxf(fmaxf(fmaxf(a0,a1),fmaxf(a2,a3)),fmaxf(a4,a5)); \
  float p01 = pk2(__expf(a0-M), __expf(a1-M)); \
  float p23 = pk2(__expf(a2-M), __expf(a3-M)); \
  float p45 = pk2(__expf(a4-M), __expf(a5-M)); \
  float s0 = dot2pk(p45, Tq2,  dot2pk(p23, Tq1,  dot2pk(p01, Tq0,  0.f))); \
  float s1 = dot2pk(p45, Tq5,  dot2pk(p23, Tq4,  dot2pk(p01, Tq3,  0.f))); \
  float s2 = dot2pk(p45, Tq8,  dot2pk(p23, Tq7,  dot2pk(p01, Tq6,  0.f))); \
  float s3 = dot2pk(p45, Tq11, dot2pk(p23, Tq10, dot2pk(p01, Tq9,  0.f))); \
  float s4 = dot2pk(p45, Tq14, dot2pk(p23, Tq13, dot2pk(p01, Tq12, 0.f))); \
  float s5 = dot2pk(p45, Tq17, dot2pk(p23, Tq16, dot2pk(p01, Tq15, 0.f))); \
  a0 = M + __logf(fmaxf(s0, 1e-37f)) + F0;  a1 = M + __logf(fmaxf(s1, 1e-37f)) + F1; \
  a2 = M + __logf(fmaxf(s2, 1e-37f)) + F2;  a3 = M + __logf(fmaxf(s3, 1e-37f)) + F3; \
  a4 = M + __logf(fmaxf(s4, 1e-37f)) + F4;  a5 = M + __logf(fmaxf(s5, 1e-37f)) + F5; \
  LOADSTAGE(X0,X1,X2,Y0,Y1,Y2, (srow) + 2); }while(0)

__global__ __launch_bounds__(256) void k_crf_scan(
    const float* __restrict__ featsF, const float* __restrict__ featsB,
    const float* __restrict__ trans, const int* __restrict__ tags,
    float* __restrict__ crfM, float* __restrict__ pgold){
  __shared__ float tr_sh[36];
  __shared__ u32 etp_sh[18];
  const int tid = threadIdx.x;
  if (tid < 36) tr_sh[tid] = trans[tid];
  if (tid < 18) etp_sh[tid] = __float_as_uint(
      pk2(__expf(trans[2 * tid]), __expf(trans[2 * tid + 1])));
  __syncthreads();
  const int bx = blockIdx.x;

  if (bx < 96){
    const int g = bx * 256 + tid;
    const int s0i = g % 6;
    const int c = (g / 6) % NCH;
    const int b = g / (6 * NCH);
    const int cbase = c * CHL;

    float Tq0=__int_as_float(etp_sh[0]),  Tq1=__int_as_float(etp_sh[1]),
          Tq2=__int_as_float(etp_sh[2]),  Tq3=__int_as_float(etp_sh[3]),
          Tq4=__int_as_float(etp_sh[4]),  Tq5=__int_as_float(etp_sh[5]),
          Tq6=__int_as_float(etp_sh[6]),  Tq7=__int_as_float(etp_sh[7]),
          Tq8=__int_as_float(etp_sh[8]),  Tq9=__int_as_float(etp_sh[9]),
          Tq10=__int_as_float(etp_sh[10]), Tq11=__int_as_float(etp_sh[11]),
          Tq12=__int_as_float(etp_sh[12]), Tq13=__int_as_float(etp_sh[13]),
          Tq14=__int_as_float(etp_sh[14]), Tq15=__int_as_float(etp_sh[15]),
          Tq16=__int_as_float(etp_sh[16]), Tq17=__int_as_float(etp_sh[17]);

    float a0 = (s0i == 0) ? 0.f : NEGV, a1 = (s0i == 1) ? 0.f : NEGV;
    float a2 = (s0i == 2) ? 0.f : NEGV, a3 = (s0i == 3) ? 0.f : NEGV;
    float a4 = (s0i == 4) ? 0.f : NEGV, a5 = (s0i == 5) ? 0.f : NEGV;

    float2 xA0,xA1,xA2,yA0,yA1,yA2, xB0,xB1,xB2,yB0,yB1,yB2;
    LOADSTAGE(xA0,xA1,xA2,yA0,yA1,yA2, cbase + 0);
    LOADSTAGE(xB0,xB1,xB2,yB0,yB1,yB2, cbase + 1);
    for (int s = 0; s < CHL; s += 2){
      ASTEP(xA0,xA1,xA2,yA0,yA1,yA2, cbase + s);
      ASTEP(xB0,xB1,xB2,yB0,yB1,yB2, cbase + s + 1);
    }
    float* mrow = crfM + ((size_t)(b * NCH + c) * 6 + s0i) * 6;
    mrow[0] = a0; mrow[1] = a1; mrow[2] = a2;
    mrow[3] = a3; mrow[4] = a4; mrow[5] = a5;
  } else {
    const int g2 = (bx - 96) * 256 + tid;
    const int b = g2 / NCH;
    const int c = g2 % NCH;
    const int* tg = tags + (size_t)b * SS + c * CHL;
    int prev = (c == 0) ? STARTT : tg[-1];
    float acc = 0.f;
    #pragma unroll 4
    for (int s = 0; s < CHL; ++s){
      int ct = tg[s];
      size_t fo = (size_t)(c * CHL + s) * BB * TT + (size_t)b * TT + ct;
      acc += tr_sh[ct * 6 + prev] + featsF[fo] + featsB[fo];
      prev = ct;
    }
    pgold[b * NCH + c] = acc;
  }
}

// ---------------- K3b: combine 16 chunk matrices + finish -------------------
__global__ __launch_bounds__(64) void k_crf_comb(
    const float* __restrict__ crfM, const float* __restrict__ pgold,
    const float* __restrict__ trans, const int* __restrict__ tags,
    float* __restrict__ out){
  const int b = blockIdx.x * 64 + threadIdx.x;
  float v0 = NEGV, v1 = NEGV, v2 = NEGV, v3 = NEGV, v4 = 0.f, v5 = NEGV;
  for (int c = 0; c < NCH; ++c){
    const float* mb = crfM + (size_t)(b * NCH + c) * 36;
    float n[6];
    #pragma unroll
    for (int j = 0; j < 6; ++j){
      float t0 = v0 + mb[0 * 6 + j], t1 = v1 + mb[1 * 6 + j];
      float t2 = v2 + mb[2 * 6 + j], t3 = v3 + mb[3 * 6 + j];
      float t4 = v4 + mb[4 * 6 + j], t5 = v5 + mb[5 * 6 + j];
      float m = fmaxf(fmaxf(fmaxf(t0,t1),fmaxf(t2,t3)),fmaxf(t4,t5));
      float s = __expf(t0-m)+__expf(t1-m)+__expf(t2-m)
              + __expf(t3-m)+__expf(t4-m)+__expf(t5-m);
      n[j] = m + __logf(s);
    }
    v0 = n[0]; v1 = n[1]; v2 = n[2]; v3 = n[3]; v4 = n[4]; v5 = n[5];
  }
  float z0 = v0 + trans[30], z1 = v1 + trans[31], z2 = v2 + trans[32];
  float z3 = v3 + trans[33], z4 = v4 + trans[34], z5 = v5 + trans[35];
  float M2 = fmaxf(fmaxf(fmaxf(z0,z1),fmaxf(z2,z3)),fmaxf(z4,z5));
  float ss = __expf(z0-M2)+__expf(z1-M2)+__expf(z2-M2)
           + __expf(z3-M2)+__expf(z4-M2)+__expf(z5-M2);
  float fwd = M2 + __logf(ss);

  float gold = trans[STOPT * 6 + tags[(size_t)b * SS + SS - 1]];
  #pragma unroll
  for (int c = 0; c < NCH; ++c) gold += pgold[b * NCH + c];
  out[b] = fwd - gold;
}

// ---------------- launch -----------------------------------------------------
extern "C" void kernel_launch(void* const* d_in, const int* in_sizes, int n_in,
                              void* d_out, int out_size, void* d_ws, size_t ws_size,
                              hipStream_t stream){
  const int*   sentence = (const int*)  d_in[0];
  const int*   tags     = (const int*)  d_in[1];
  const float* emb      = (const float*)d_in[2];
  const float* w_ih_f   = (const float*)d_in[3];
  const float* w_hh_f   = (const float*)d_in[4];
  const float* b_ih_f   = (const float*)d_in[5];
  const float* b_hh_f   = (const float*)d_in[6];
  const float* w_ih_b   = (const float*)d_in[7];
  const float* w_hh_b   = (const float*)d_in[8];
  const float* b_ih_b   = (const float*)d_in[9];
  const float* b_hh_b   = (const float*)d_in[10];
  const float* h0       = (const float*)d_in[11];
  const float* c0       = (const float*)d_in[12];
  const float* w_out    = (const float*)d_in[13];
  const float* b_out    = (const float*)d_in[14];
  const float* trans    = (const float*)d_in[15];
  float* out = (float*)d_out;

  float* ws = (float*)d_ws;
  float* vxg    = ws;                                 // [2][8000][300] (permuted)
  float* featsF = vxg + (size_t)2 * VOCABN * G4;      // [512][256][6]
  float* featsB = featsF + (size_t)SS * BB * TT;      // [512][256][6]
  float* crfM   = featsB + (size_t)SS * BB * TT;      // [256][16][6][6]
  float* pgold  = crfM + (size_t)BB * NCH * 36;       // [256][16]

  k_gemm<<<2 * 125, 256, 0, stream>>>(emb, w_ih_f, w_ih_b,
                                      b_ih_f, b_hh_f, b_ih_b, b_hh_b, vxg);
  k_lstm<<<32, 640, 0, stream>>>(sentence, vxg, w_hh_f, w_hh_b, h0, c0, w_out, b_out,
                                 featsF, featsB);
  k_crf_scan<<<96 + 16, 256, 0, stream>>>(featsF, featsB, trans, tags, crfM, pgold);
  k_crf_comb<<<BB / 64, 64, 0, stream>>>(crfM, pgold, trans, tags, out);
}